// Round 9
// baseline (393.965 us; speedup 1.0000x reference)
//
#include <hip/hip_runtime.h>

// SCVC: out[n,o,i,j] = sum_{c,d} x[n,c,i] y[n,d,j] Cr[o,c,d]
//                      + a[n,o,i] + b[n,o,j] + bias[o]
// N=32, IN1=IN2=4, OUT=128, DX=DY=128. All float32. 268 MB output, ~130 KB in.
//
// Ledger: R0 base 266.4 | R1 clamp artifact | R3 nt +7 | R4 o-pair 264.7 |
// R5 wave-linear 263.1 | R6 2-blocks/CU streams 299 | R7/R8 infra failures
// (container acquisition; kernel audited in-bounds, never executed).
//
// R9 == R7 experiment, third attempt: DRAM row-buffer locality of the GLOBAL
// write front. Wave w owns (o=w>>6, rowpair k=w&63), loops n=0..31 outermost
// -> at any instant all 8192 waves write inside ONE contiguous 8 MB n-slice
// that sweeps the output (fill-shaped front), vs ~2048 scattered 1KB lines in
// all tile-confined variants. No LDS, no barriers; each wave recomputes its
// row terms in registers (~88 VALU per 1KB store).
// Contingency: a third infra failure => kernel-correlated; revert to R5 next.

__global__ __launch_bounds__(256) void scvc_kernel(
    const float* __restrict__ x,     // [32,4,128]
    const float* __restrict__ y,     // [32,4,128]
    const float* __restrict__ C,     // [128,16]
    const float* __restrict__ WA,    // [128,16,2]
    const float* __restrict__ WB,    // [128,16,2]
    const float* __restrict__ bias,  // [128]
    float* __restrict__ out)         // [32,128,128,128]
{
    const int wg   = (blockIdx.x << 2) + (threadIdx.x >> 6);  // 0..8191
    const int lane = threadIdx.x & 63;
    const int o    = wg >> 6;            // 0..127 (block-uniform)
    const int k    = wg & 63;            // row-pair index
    const int half = lane >> 5;          // 0/1
    const int i    = (k << 1) + half;    // own output row 0..127
    const int col4 = (lane & 31) << 2;   // own 4 cols: 0,4,...,124

    // ---- wave-uniform weights, folded once (amortized over 32 stores) ----
    float cr[4][4];                      // Cr[c][d]
    #pragma unroll
    for (int c = 0; c < 4; ++c) {
        #pragma unroll
        for (int d = 0; d < 4; ++d)
            cr[c][d] = C[o * 16 + c * 4 + d];
    }

    float wam[4], wap[4], wbm[4], wbp[4];
    const float mm = (i > 0)   ? 1.f : 0.f;   // own-row conv edge masks
    const float mp = (i < 127) ? 1.f : 0.f;
    #pragma unroll
    for (int c = 0; c < 4; ++c) {
        float sa0 = 0.f, sa1 = 0.f, sb0 = 0.f, sb1 = 0.f;
        #pragma unroll
        for (int r = 0; r < 4; ++r) {         // fold the channel-tile repeat
            sa0 += WA[o * 32 + (4 * r + c) * 2 + 0];
            sa1 += WA[o * 32 + (4 * r + c) * 2 + 1];
            sb0 += WB[o * 32 + (4 * r + c) * 2 + 0];
            sb1 += WB[o * 32 + (4 * r + c) * 2 + 1];
        }
        wam[c] = sa0 * mm;   // x-side taps, edge mask folded in
        wap[c] = sa1 * mp;
        wbm[c] = sb0;        // y-side taps (col edges masked per-lane below)
        wbp[c] = sb1;
    }
    const float bo = bias[o];

    // clamped-index + value-mask edge handling (loads always in bounds)
    const int   im = (i > 0)      ? i - 1    : 0;
    const int   ip = (i < 127)    ? i + 1    : 0;
    const float cm = (col4 > 0)   ? 1.f : 0.f;
    const float cp = (col4 < 124) ? 1.f : 0.f;
    const int   jm = (col4 > 0)   ? col4 - 1 : 0;
    const int   jp = (col4 < 124) ? col4 + 4 : 0;

    // out offset for (n, o, i, col4): n*2097152 + o*16384 + i*128 + col4
    float* op = out + (long)o * 16384 + i * 128 + col4;

    #pragma unroll 2
    for (int n = 0; n < 32; ++n) {
        const float* xb = x + (n << 9);
        const float* yb = y + (n << 9);

        // own-row t4[d] = sum_c x[c,i]*cr[c][d]; a = own-row conv
        float t40 = 0.f, t41 = 0.f, t42 = 0.f, t43 = 0.f, a = 0.f;
        #pragma unroll
        for (int c = 0; c < 4; ++c) {
            const float xc = xb[(c << 7) + i];      // broadcast within half-wave
            t40 = fmaf(xc, cr[c][0], t40);
            t41 = fmaf(xc, cr[c][1], t41);
            t42 = fmaf(xc, cr[c][2], t42);
            t43 = fmaf(xc, cr[c][3], t43);
            a = fmaf(xb[(c << 7) + im], wam[c], a);
            a = fmaf(xb[(c << 7) + ip], wap[c], a);
        }

        // own-cols y tile + col conv (bj includes bias)
        float bj0 = bo, bj1 = bo, bj2 = bo, bj3 = bo;
        float yr[4][4];
        #pragma unroll
        for (int d = 0; d < 4; ++d) {
            const float4 v = *(const float4*)(yb + (d << 7) + col4);
            yr[d][0] = v.x; yr[d][1] = v.y; yr[d][2] = v.z; yr[d][3] = v.w;
            const float ymv = yb[(d << 7) + jm] * cm;   // y[d][col4-1]
            const float ypv = yb[(d << 7) + jp] * cp;   // y[d][col4+4]
            bj0 = fmaf(ymv, wbm[d], bj0); bj0 = fmaf(v.y, wbp[d], bj0);
            bj1 = fmaf(v.x, wbm[d], bj1); bj1 = fmaf(v.z, wbp[d], bj1);
            bj2 = fmaf(v.y, wbm[d], bj2); bj2 = fmaf(v.w, wbp[d], bj2);
            bj3 = fmaf(v.z, wbm[d], bj3); bj3 = fmaf(ypv, wbp[d], bj3);
        }

        float4 r;
        r.x = t40 * yr[0][0] + t41 * yr[1][0] + t42 * yr[2][0] + t43 * yr[3][0] + (a + bj0);
        r.y = t40 * yr[0][1] + t41 * yr[1][1] + t42 * yr[2][1] + t43 * yr[3][1] + (a + bj1);
        r.z = t40 * yr[0][2] + t41 * yr[1][2] + t42 * yr[2][2] + t43 * yr[3][2] + (a + bj2);
        r.w = t40 * yr[0][3] + t41 * yr[1][3] + t42 * yr[2][3] + t43 * yr[3][3] + (a + bj3);
        *(float4*)op = r;            // 1 KB dense line per wave-instr
        op += 2097152;               // next n: the whole grid sweeps together
    }
}

extern "C" void kernel_launch(void* const* d_in, const int* in_sizes, int n_in,
                              void* d_out, int out_size, void* d_ws, size_t ws_size,
                              hipStream_t stream) {
    const float* x    = (const float*)d_in[0];
    const float* y    = (const float*)d_in[1];
    const float* C    = (const float*)d_in[2];
    const float* WA   = (const float*)d_in[3];
    const float* WB   = (const float*)d_in[4];
    const float* bias = (const float*)d_in[5];
    float* out = (float*)d_out;

    scvc_kernel<<<2048, 256, 0, stream>>>(x, y, C, WA, WB, bias, out);
}

// Round 10
// 281.352 us; speedup vs baseline: 1.4003x; 1.4003x over previous
//
#include <hip/hip_runtime.h>

// SCVC: out[n,o,i,j] = sum_{c,d} x[n,c,i] y[n,d,j] Cr[o,c,d]
//                      + a[n,o,i] + b[n,o,j] + bias[o]
// N=32, IN1=IN2=4, OUT=128, DX=DY=128. All float32. 268 MB output, ~130 KB in.
//
// Ledger: R0 base 266.4 | R3 nt +7 | R4 o-pair 264.7 | R5 wave-linear 263.1 |
// R6 2-blocks/CU 299 | R9 sweep-front 189us KERNEL-MEASURED (1.4 TB/s):
// 20 VMEM loads per 1KB store saturated the TA/L1 pipe -> stores throttled.
// R9 counters recalibrated the ledger: harness overhead ~43us + fill ~162us
// -> tile-confined kernel is ~60us (4.4 TB/s) vs 41us fill-rate floor.
//
// R10: R5's math with ZERO barriers and ZERO LDS, load-light. Block = (n,o);
// all weights are wave-uniform -> s_load (no TA traffic); y-tile + col-conv
// bj computed once per block into regs. Per row: 12 broadcast x-loads
// (~36 TA-cy) + ~26 FMA -> one 1KB store (16 TA-cy): 3.5x TA headroom,
// unlike R9's 7.7:1 inversion. Blocks free-run -> store streams ramp and
// overlap instead of one synchronized phase->store generation.

__global__ __launch_bounds__(256) void scvc_kernel(
    const float* __restrict__ x,     // [32,4,128]
    const float* __restrict__ y,     // [32,4,128]
    const float* __restrict__ C,     // [128,16]
    const float* __restrict__ WA,    // [128,16,2]
    const float* __restrict__ WB,    // [128,16,2]
    const float* __restrict__ bias,  // [128]
    float* __restrict__ out)         // [32,128,128,128]
{
    const int n    = blockIdx.x >> 7;    // 0..31
    const int o    = blockIdx.x & 127;   // 0..127 (block-uniform)
    const int tid  = threadIdx.x;
    const int wave = tid >> 6;           // 0..3: owns rows [32w, 32w+32)
    const int lane = tid & 63;
    const int half = lane >> 5;          // 0/1
    const int col4 = (lane & 31) << 2;   // own 4 cols: 0,4,...,124
    const int r0   = wave << 5;

    const float* xb = x + (n << 9);
    const float* yb = y + (n << 9);

    // ---- block-uniform weights: compiler emits scalar loads (no TA traffic)
    float cr[4][4];                      // Cr[c][d]
    #pragma unroll
    for (int c = 0; c < 4; ++c) {
        #pragma unroll
        for (int d = 0; d < 4; ++d)
            cr[c][d] = C[o * 16 + c * 4 + d];
    }
    float wam[4], wap[4], wbm[4], wbp[4];
    #pragma unroll
    for (int c = 0; c < 4; ++c) {
        float sa0 = 0.f, sa1 = 0.f, sb0 = 0.f, sb1 = 0.f;
        #pragma unroll
        for (int r = 0; r < 4; ++r) {    // fold the channel-tile repeat
            sa0 += WA[o * 32 + (4 * r + c) * 2 + 0];
            sa1 += WA[o * 32 + (4 * r + c) * 2 + 1];
            sb0 += WB[o * 32 + (4 * r + c) * 2 + 0];
            sb1 += WB[o * 32 + (4 * r + c) * 2 + 1];
        }
        wam[c] = sa0; wap[c] = sa1; wbm[c] = sb0; wbp[c] = sb1;
    }
    const float bo = bias[o];

    // ---- per-lane y tile + column conv (once per block, kept in regs) ----
    const float cm = (col4 > 0)   ? 1.f : 0.f;
    const float cp = (col4 < 124) ? 1.f : 0.f;
    const int   jm = (col4 > 0)   ? col4 - 1 : 0;
    const int   jp = (col4 < 124) ? col4 + 4 : 0;

    float yr[4][4];
    float bj0 = bo, bj1 = bo, bj2 = bo, bj3 = bo;
    #pragma unroll
    for (int d = 0; d < 4; ++d) {
        const float4 v = *(const float4*)(yb + (d << 7) + col4);
        yr[d][0] = v.x; yr[d][1] = v.y; yr[d][2] = v.z; yr[d][3] = v.w;
        const float ymv = yb[(d << 7) + jm] * cm;   // y[d][col4-1]
        const float ypv = yb[(d << 7) + jp] * cp;   // y[d][col4+4]
        bj0 = fmaf(ymv,     wbm[d], bj0); bj0 = fmaf(v.y, wbp[d], bj0);
        bj1 = fmaf(v.x,     wbm[d], bj1); bj1 = fmaf(v.z, wbp[d], bj1);
        bj2 = fmaf(v.y,     wbm[d], bj2); bj2 = fmaf(v.w, wbp[d], bj2);
        bj3 = fmaf(v.z,     wbm[d], bj3); bj3 = fmaf(ypv, wbp[d], bj3);
    }

    // ---- store stream: 32 rows per wave, contiguous 32 KB run, no barriers.
    // Store instr covers rows {r0+2it, r0+2it+1} = dense 1 KB line.
    float* op = out + ((long)blockIdx.x << 14) + (r0 << 7) + (half << 7) + col4;

    #pragma unroll 4
    for (int it = 0; it < 16; ++it) {
        const int i = r0 + (it << 1) + half;
        const int im = (i > 0)   ? i - 1 : 0;        // clamped conv taps
        const int ip = (i < 127) ? i + 1 : 127;
        const float mm = (i > 0)   ? 1.f : 0.f;
        const float mp = (i < 127) ? 1.f : 0.f;

        float t40 = 0.f, t41 = 0.f, t42 = 0.f, t43 = 0.f;
        float am = 0.f, ap = 0.f;
        #pragma unroll
        for (int c = 0; c < 4; ++c) {
            const float xc = xb[(c << 7) + i];       // broadcast-address load
            t40 = fmaf(xc, cr[c][0], t40);
            t41 = fmaf(xc, cr[c][1], t41);
            t42 = fmaf(xc, cr[c][2], t42);
            t43 = fmaf(xc, cr[c][3], t43);
            am  = fmaf(xb[(c << 7) + im], wam[c], am);
            ap  = fmaf(xb[(c << 7) + ip], wap[c], ap);
        }
        const float a = mm * am + mp * ap;

        float4 r;
        r.x = t40 * yr[0][0] + t41 * yr[1][0] + t42 * yr[2][0] + t43 * yr[3][0] + (a + bj0);
        r.y = t40 * yr[0][1] + t41 * yr[1][1] + t42 * yr[2][1] + t43 * yr[3][1] + (a + bj1);
        r.z = t40 * yr[0][2] + t41 * yr[1][2] + t42 * yr[2][2] + t43 * yr[3][2] + (a + bj2);
        r.w = t40 * yr[0][3] + t41 * yr[1][3] + t42 * yr[2][3] + t43 * yr[3][3] + (a + bj3);
        *(float4*)op = r;          // dense 1 KB line per wave-instr
        op += 256;                 // next row pair (contiguous)
    }
}

extern "C" void kernel_launch(void* const* d_in, const int* in_sizes, int n_in,
                              void* d_out, int out_size, void* d_ws, size_t ws_size,
                              hipStream_t stream) {
    const float* x    = (const float*)d_in[0];
    const float* y    = (const float*)d_in[1];
    const float* C    = (const float*)d_in[2];
    const float* WA   = (const float*)d_in[3];
    const float* WB   = (const float*)d_in[4];
    const float* bias = (const float*)d_in[5];
    float* out = (float*)d_out;

    scvc_kernel<<<32 * 128, 256, 0, stream>>>(x, y, C, WA, WB, bias, out);
}

// Round 12
// 262.972 us; speedup vs baseline: 1.4981x; 1.0699x over previous
//
#include <hip/hip_runtime.h>

// SCVC: out[n,o,i,j] = sum_{c,d} x[n,c,i] y[n,d,j] Cr[o,c,d]
//                      + a[n,o,i] + b[n,o,j] + bias[o]
// N=32, IN1=IN2=4, OUT=128, DX=DY=128. All float32. 268 MB output, ~130 KB in.
//
// Ledger (kernel-part, 43us harness const + fill calibrated in R9):
//   R0/R4/R5 LDS-phase + dense wave stores: 58-61us  <- plateau, best
//   R6 2-blocks/CU 95 | R9 sweep-front 189 (load-heavy) | R10 no-LDS 76.
// Store floor 41us (fill rate 6.5 TB/s). Every structural deviation regressed.
// R11 infra-failed twice (container acquisition; same class as R7/R8, which
// later ran clean in R9) -> resubmit unchanged.
//
// R12 == R11: strict removal on the winning R5 structure. Weight folds are
// block-uniform -> fold in REGISTERS via scalar loads (R10 proved the path;
// its loss was per-iter loads, not the fold). Eliminates phase0 LDS + one of
// two barriers; y-tile loads hoisted above the fold to overlap latency.
// Store loop (proven) untouched: wave w owns rows [32w,32w+32), dense 1KB
// lines, contiguous 32KB run per wave.

__global__ __launch_bounds__(256) void scvc_kernel(
    const float* __restrict__ x,     // [32,4,128]
    const float* __restrict__ y,     // [32,4,128]
    const float* __restrict__ C,     // [128,16]
    const float* __restrict__ WA,    // [128,16,2]
    const float* __restrict__ WB,    // [128,16,2]
    const float* __restrict__ bias,  // [128]
    float* __restrict__ out)         // [32,128,128,128]
{
    const int n    = blockIdx.x >> 7;    // 0..31
    const int o    = blockIdx.x & 127;   // 0..127 (block-uniform)
    const int tid  = threadIdx.x;
    const int wave = tid >> 6;           // 0..3: owns rows [32w, 32w+32)
    const int lane = tid & 63;
    const int half = lane >> 5;          // 0/1
    const int col4 = (lane & 31) << 2;   // own 4 cols: 0,4,...,124
    const int r0   = wave << 5;

    __shared__ float t4[128][4];    // t4[i][d] = sum_c x[c,i]*Cr[c,d]
    __shared__ float arow[128];
    __shared__ float bcol[128];     // includes bias

    const float* xb = x + (n << 9);
    const float* yb = y + (n << 9);

    // ---- y tile: issue first so the loads are in flight under the fold ----
    float yr[4][4];
    #pragma unroll
    for (int d = 0; d < 4; ++d) {
        const float4 v = *(const float4*)(yb + (d << 7) + col4);
        yr[d][0] = v.x; yr[d][1] = v.y; yr[d][2] = v.z; yr[d][3] = v.w;
    }

    // ---- block-uniform weight folds in registers (scalar loads, no LDS) ----
    float cr[4][4];                      // Cr[c][d]
    #pragma unroll
    for (int c = 0; c < 4; ++c) {
        #pragma unroll
        for (int d = 0; d < 4; ++d)
            cr[c][d] = C[o * 16 + c * 4 + d];
    }
    float wam[4], wap[4], wbm[4], wbp[4];
    #pragma unroll
    for (int c = 0; c < 4; ++c) {
        float sa0 = 0.f, sa1 = 0.f, sb0 = 0.f, sb1 = 0.f;
        #pragma unroll
        for (int r = 0; r < 4; ++r) {    // fold the channel-tile repeat
            sa0 += WA[o * 32 + (4 * r + c) * 2 + 0];
            sa1 += WA[o * 32 + (4 * r + c) * 2 + 1];
            sb0 += WB[o * 32 + (4 * r + c) * 2 + 0];
            sb1 += WB[o * 32 + (4 * r + c) * 2 + 1];
        }
        wam[c] = sa0; wap[c] = sa1; wbm[c] = sb0; wbp[c] = sb1;
    }
    const float bo = bias[o];

    // ---- phase 1: rows (threads 0..127) / cols (128..255), ONE barrier ----
    if (tid < 128) {
        const int i = tid;
        float xv[4], xm[4], xp[4];
        #pragma unroll
        for (int c = 0; c < 4; ++c) {
            xv[c] = xb[(c << 7) + i];
            xm[c] = (i > 0)   ? xb[(c << 7) + i - 1] : 0.f;  // conv tap t-1
            xp[c] = (i < 127) ? xb[(c << 7) + i + 1] : 0.f;  // conv tap t+1
        }
        #pragma unroll
        for (int d = 0; d < 4; ++d) {
            float s = 0.f;
            #pragma unroll
            for (int c = 0; c < 4; ++c) s = fmaf(xv[c], cr[c][d], s);
            t4[i][d] = s;
        }
        float a = 0.f;
        #pragma unroll
        for (int c = 0; c < 4; ++c) {
            a = fmaf(xm[c], wam[c], a);
            a = fmaf(xp[c], wap[c], a);
        }
        arow[i] = a;
    } else {
        const int j = tid - 128;
        float b = bo;
        #pragma unroll
        for (int c = 0; c < 4; ++c) {
            const float ym = (j > 0)   ? yb[(c << 7) + j - 1] : 0.f;
            const float yp = (j < 127) ? yb[(c << 7) + j + 1] : 0.f;
            b = fmaf(ym, wbm[c], b);
            b = fmaf(yp, wbp[c], b);
        }
        bcol[j] = b;
    }
    __syncthreads();

    // ---- store stream (unchanged, proven): dense 1 KB lines, 32 KB/wave ----
    const float4 bv = *(const float4*)(&bcol[col4]);
    const float bj0 = bv.x, bj1 = bv.y, bj2 = bv.z, bj3 = bv.w;

    float* op = out + ((long)blockIdx.x << 14) + (r0 << 7) + (half << 7) + col4;
    #pragma unroll
    for (int it = 0; it < 16; ++it) {
        const int i = r0 + (it << 1) + half;
        const float4 t = *(const float4*)(&t4[i][0]);   // broadcast ds_read_b128
        const float ai = arow[i];
        float4 r;
        r.x = t.x * yr[0][0] + t.y * yr[1][0] + t.z * yr[2][0] + t.w * yr[3][0] + (ai + bj0);
        r.y = t.x * yr[0][1] + t.y * yr[1][1] + t.z * yr[2][1] + t.w * yr[3][1] + (ai + bj1);
        r.z = t.x * yr[0][2] + t.y * yr[1][2] + t.z * yr[2][2] + t.w * yr[3][2] + (ai + bj2);
        r.w = t.x * yr[0][3] + t.y * yr[1][3] + t.z * yr[2][3] + t.w * yr[3][3] + (ai + bj3);
        *(float4*)op = r;          // dense 1 KB line per wave-instr
        op += 256;                 // next row pair (contiguous per wave)
    }
}

extern "C" void kernel_launch(void* const* d_in, const int* in_sizes, int n_in,
                              void* d_out, int out_size, void* d_ws, size_t ws_size,
                              hipStream_t stream) {
    const float* x    = (const float*)d_in[0];
    const float* y    = (const float*)d_in[1];
    const float* C    = (const float*)d_in[2];
    const float* WA   = (const float*)d_in[3];
    const float* WB   = (const float*)d_in[4];
    const float* bias = (const float*)d_in[5];
    float* out = (float*)d_out;

    scvc_kernel<<<32 * 128, 256, 0, stream>>>(x, y, C, WA, WB, bias, out);
}